// Round 4
// baseline (556.849 us; speedup 1.0000x reference)
//
#include <hip/hip_runtime.h>
#include <math.h>

#define NCOL 64
#define M_ROWS 262144

__device__ __forceinline__ void cmac_conj(float2& acc, const float2 a, const float2 b) {
    // acc += conj(a) * b
    acc.x = fmaf(a.x, b.x, acc.x);
    acc.x = fmaf(a.y, b.y, acc.x);
    acc.y = fmaf(a.x, b.y, acc.y);
    acc.y = fmaf(-a.y, b.x, acc.y);
}
__device__ __forceinline__ void cmac(float2& acc, const float2 a, const float2 b) {
    // acc += a * b
    acc.x = fmaf(a.x, b.x, acc.x);
    acc.x = fmaf(-a.y, b.y, acc.x);
    acc.y = fmaf(a.x, b.y, acc.y);
    acc.y = fmaf(a.y, b.x, acc.y);
}

// ---------------- G = X^H X, upper-triangle groups only ----------------
#define GR_BLOCKS 2048
#define GR_ROWS (M_ROWS / GR_BLOCKS)   // 128
#define GR_TROWS 32

__global__ __launch_bounds__(256) void gram_kernel(const float4* __restrict__ X4,
                                                   float* __restrict__ Gbufs, int bufmask) {
    __shared__ float2 tile[GR_TROWS][66];
    const int t = threadIdx.x;
    const int j1 = t >> 4;   // G rows j1+{0,16,32,48}
    const int k1 = t & 15;   // G cols k1+{0,16,32,48}
    float2 acc[4][4];
#pragma unroll
    for (int a = 0; a < 4; ++a)
#pragma unroll
        for (int b = 0; b < 4; ++b) acc[a][b] = make_float2(0.f, 0.f);

    const int rbeg = blockIdx.x * GR_ROWS;
    for (int t0 = 0; t0 < GR_ROWS; t0 += GR_TROWS) {
        const float4* src = X4 + (size_t)(rbeg + t0) * (NCOL / 2);
#pragma unroll
        for (int i = 0; i < 4; ++i) {
            const int f = t + 256 * i;     // 1024 float4 = 32 rows x 32 float4
            const int row = f >> 5;
            const int c4 = f & 31;
            *reinterpret_cast<float4*>(&tile[row][c4 * 2]) = src[f];
        }
        __syncthreads();
#pragma unroll 2
        for (int r = 0; r < GR_TROWS; ++r) {
            float2 xa[4], xb[4];
#pragma unroll
            for (int a = 0; a < 4; ++a) xa[a] = tile[r][j1 + 16 * a];
#pragma unroll
            for (int b = 0; b < 4; ++b) xb[b] = tile[r][k1 + 16 * b];
            // Cholesky only reads the upper triangle of G: skip groups a > b.
#pragma unroll
            for (int a = 0; a < 4; ++a)
#pragma unroll
                for (int b = 0; b < 4; ++b)
                    if (a <= b) cmac_conj(acc[a][b], xa[a], xb[b]);
        }
        __syncthreads();
    }
    float* G = Gbufs + (size_t)(blockIdx.x & bufmask) * 8192;
#pragma unroll
    for (int a = 0; a < 4; ++a)
#pragma unroll
        for (int b = 0; b < 4; ++b)
            if (a <= b) {
                const int idx = (j1 + 16 * a) * NCOL + (k1 + 16 * b);
                atomicAdd(&G[2 * idx], acc[a][b].x);
                atomicAdd(&G[2 * idx + 1], acc[a][b].y);
            }
}

// ---------------- single-wave LDS: reduce + Cholesky + triangular inverse ----------------
// Lane k owns column k. A is 64x64 float2 (64 KB LDS), rolled loops, no spill.
// After Cholesky: upper(A) = R, diag packs {d, dinv}. Lower triangle of A is then
// reused to hold W = R^{-1} transposed: W[i][k] (i<k) stored at A[k*64+i].
__global__ __launch_bounds__(64) void cholinv_kernel(const float* __restrict__ Gbufs, int nbuf,
                                                     float2* __restrict__ RinvOut) {
    __shared__ float2 A[64 * 64];
    const int k = threadIdx.x;

    // 1) reduce partial G buffers into A
    {
        float4* A4 = reinterpret_cast<float4*>(A);
        const float4* Gb4 = reinterpret_cast<const float4*>(Gbufs);
        for (int it = 0; it < 32; ++it) {
            const int f = k + 64 * it;      // 2048 float4
            float4 s = Gb4[f];
            for (int b = 1; b < nbuf; ++b) {
                const float4 u = Gb4[b * 2048 + f];
                s.x += u.x; s.y += u.y; s.z += u.z; s.w += u.w;
            }
            A4[f] = s;
        }
    }
    __syncthreads();

    // 2) Cholesky, single wave, no barriers. Uniform reads broadcast; per-lane
    //    column reads are 2-way bank aliases (free).
    for (int i = 0; i < 64; ++i) {
        const float dsq = A[i * 64 + i].x;            // uniform broadcast
        const float d = sqrtf(fmaxf(dsq, 1e-30f));
        const float dinv = 1.0f / d;
        float2 rr = A[i * 64 + k];                    // row i, this lane's column
        rr.x *= dinv; rr.y *= dinv;
        if (k == i) { rr.x = d; rr.y = dinv; }        // pack {d, dinv} on diag
        A[i * 64 + k] = rr;                           // scaled row i = R[i][:]
        // trailing update: A[j][k] -= conj(R[i][j]) * R[i][k]  (garbage in lower
        // triangle columns k <= i is never read)
#pragma unroll 4
        for (int j = i + 1; j < 64; ++j) {
            const float2 rij = A[i * 64 + j];         // uniform (valid: j > i)
            float2 v = A[j * 64 + k];
            v.x = fmaf(-rij.x, rr.x, fmaf(-rij.y, rr.y, v.x));
            v.y = fmaf(-rij.x, rr.y, fmaf( rij.y, rr.x, v.y));
            A[j * 64 + k] = v;
        }
    }
    __syncthreads();

    // 3) back-substitution: lane k solves R * w = e_k * (column k of R^{-1}).
    //    W[i][k] (i<k) stored transposed at A[k*64+i] (strictly-lower, disjoint
    //    from R's upper+diag). W[k][k] = dinv_k implicit; W[j][k] = 0 for j > k.
    const float dk = A[k * 64 + k].y;                 // dinv_k
    for (int ii = 0; ii < 63; ++ii) {
        const int i = 62 - ii;
        float2 s0 = make_float2(0.f, 0.f), s1 = make_float2(0.f, 0.f);
        if (i < k) {                                  // j == k peel: R[i][k] * dinv_k
            const float2 rik = A[i * 64 + k];
            s0.x = rik.x * dk;
            s0.y = rik.y * dk;
        }
        int j = i + 1;
        for (; j + 1 < 64; j += 2) {
            {
                float2 w = A[k * 64 + j];             // W[j][k], valid only j < k
                const bool val = (j < k);
                w.x = val ? w.x : 0.f; w.y = val ? w.y : 0.f;
                const float2 rij = A[i * 64 + j];     // uniform
                cmac(s0, rij, w);
            }
            {
                const int j2 = j + 1;
                float2 w = A[k * 64 + j2];
                const bool val = (j2 < k);
                w.x = val ? w.x : 0.f; w.y = val ? w.y : 0.f;
                const float2 rij = A[i * 64 + j2];
                cmac(s1, rij, w);
            }
        }
        if (j < 64) {
            float2 w = A[k * 64 + j];
            const bool val = (j < k);
            w.x = val ? w.x : 0.f; w.y = val ? w.y : 0.f;
            const float2 rij = A[i * 64 + j];
            cmac(s0, rij, w);
        }
        const float di = A[i * 64 + i].y;             // dinv_i (uniform)
        if (i < k) {
            A[k * 64 + i] = make_float2(-di * (s0.x + s1.x), -di * (s0.y + s1.y));
        }
    }
    __syncthreads();

    // 4) write Rinv with exact zeros below the diagonal (apply relies on them)
    for (int i = 0; i < 64; ++i) {
        float2 v = A[k * 64 + i];
        if (i >= k) v = make_float2(0.f, 0.f);
        if (i == k) v.x = dk;
        RinvOut[i * 64 + k] = v;
    }
}

// ---------------- Q = X * Rinv (triangular j-loop) ----------------
#define AP_BLOCKS 2048
#define AP_ROWS (M_ROWS / AP_BLOCKS)   // 128
#define AP_TROWS 32

__global__ __launch_bounds__(256) void apply_kernel(const float4* __restrict__ X4,
                                                    const float4* __restrict__ Rinv4,
                                                    float2* __restrict__ Q2) {
    __shared__ float2 W[64][64];
    __shared__ float2 tile[AP_TROWS][66];
    const int t = threadIdx.x;
#pragma unroll
    for (int i = 0; i < 8; ++i) {
        const int f = t + 256 * i;
        reinterpret_cast<float4*>(&W[0][0])[f] = Rinv4[f];
    }
    const int k1 = t & 15;
    const int r1 = t >> 4;
    const int rbeg = blockIdx.x * AP_ROWS;
    for (int t0 = 0; t0 < AP_ROWS; t0 += AP_TROWS) {
        const float4* src = X4 + (size_t)(rbeg + t0) * (NCOL / 2);
#pragma unroll
        for (int i = 0; i < 4; ++i) {
            const int f = t + 256 * i;
            const int row = f >> 5;
            const int c4 = f & 31;
            *reinterpret_cast<float4*>(&tile[row][c4 * 2]) = src[f];
        }
        __syncthreads();
        float2 acc[2][4];
#pragma unroll
        for (int a = 0; a < 2; ++a)
#pragma unroll
            for (int b = 0; b < 4; ++b) acc[a][b] = make_float2(0.f, 0.f);

#define SEG(JLO, JHI, BMIN)                                          \
        _Pragma("unroll 2")                                          \
        for (int j = (JLO); j < (JHI); ++j) {                        \
            const float2 x0 = tile[r1][j];                           \
            const float2 x1 = tile[r1 + 16][j];                      \
            _Pragma("unroll")                                        \
            for (int b = (BMIN); b < 4; ++b) {                       \
                const float2 w = W[j][k1 + 16 * b];                  \
                cmac(acc[0][b], x0, w);                              \
                cmac(acc[1][b], x1, w);                              \
            }                                                        \
        }
        SEG(0, 16, 0)
        SEG(16, 32, 1)
        SEG(32, 48, 2)
        SEG(48, 64, 3)
#undef SEG

#pragma unroll
        for (int a = 0; a < 2; ++a) {
            const size_t row = (size_t)(rbeg + t0 + r1 + 16 * a);
#pragma unroll
            for (int b = 0; b < 4; ++b) Q2[row * NCOL + k1 + 16 * b] = acc[a][b];
        }
        __syncthreads();
    }
}

extern "C" void kernel_launch(void* const* d_in, const int* in_sizes, int n_in,
                              void* d_out, int out_size, void* d_ws, size_t ws_size,
                              hipStream_t stream) {
    (void)in_sizes; (void)n_in; (void)out_size;
    const float4* X4 = reinterpret_cast<const float4*>(d_in[0]);
    float* Gbufs = reinterpret_cast<float*>(d_ws);
    int nbuf = 1;
    while (nbuf < 16 && (size_t)(2 * nbuf) * 32768 + 32768 <= ws_size) nbuf <<= 1;
    float2* Rinv = reinterpret_cast<float2*>((char*)d_ws + (size_t)nbuf * 32768);

    hipMemsetAsync(Gbufs, 0, (size_t)nbuf * 32768, stream);
    gram_kernel<<<GR_BLOCKS, 256, 0, stream>>>(X4, Gbufs, nbuf - 1);
    cholinv_kernel<<<1, 64, 0, stream>>>(Gbufs, nbuf, Rinv);
    apply_kernel<<<AP_BLOCKS, 256, 0, stream>>>(X4, reinterpret_cast<const float4*>(Rinv),
                                                reinterpret_cast<float2*>(d_out));
}

// Round 5
// 427.036 us; speedup vs baseline: 1.3040x; 1.3040x over previous
//
#include <hip/hip_runtime.h>
#include <math.h>

#define NCOL 64
#define M_ROWS 262144

__device__ __forceinline__ void cmac_conj(float2& acc, const float2 a, const float2 b) {
    // acc += conj(a) * b
    acc.x = fmaf(a.x, b.x, acc.x);
    acc.x = fmaf(a.y, b.y, acc.x);
    acc.y = fmaf(a.x, b.y, acc.y);
    acc.y = fmaf(-a.y, b.x, acc.y);
}
__device__ __forceinline__ void cmac(float2& acc, const float2 a, const float2 b) {
    // acc += a * b
    acc.x = fmaf(a.x, b.x, acc.x);
    acc.x = fmaf(-a.y, b.y, acc.x);
    acc.y = fmaf(a.x, b.y, acc.y);
    acc.y = fmaf(a.y, b.x, acc.y);
}
__device__ __forceinline__ float lane_bcast(float v, int lane) {
    return __uint_as_float(__builtin_amdgcn_readlane(__float_as_uint(v), lane));
}

// ---------------- G = X^H X, upper-triangle groups only ----------------
#define GR_BLOCKS 2048
#define GR_ROWS (M_ROWS / GR_BLOCKS)   // 128
#define GR_TROWS 32

__global__ __launch_bounds__(256) void gram_kernel(const float4* __restrict__ X4,
                                                   float* __restrict__ Gbufs, int bufmask) {
    __shared__ float2 tile[GR_TROWS][66];
    const int t = threadIdx.x;
    const int j1 = t >> 4;   // G rows j1+{0,16,32,48}
    const int k1 = t & 15;   // G cols k1+{0,16,32,48}
    float2 acc[4][4];
#pragma unroll
    for (int a = 0; a < 4; ++a)
#pragma unroll
        for (int b = 0; b < 4; ++b) acc[a][b] = make_float2(0.f, 0.f);

    const int rbeg = blockIdx.x * GR_ROWS;
    for (int t0 = 0; t0 < GR_ROWS; t0 += GR_TROWS) {
        const float4* src = X4 + (size_t)(rbeg + t0) * (NCOL / 2);
#pragma unroll
        for (int i = 0; i < 4; ++i) {
            const int f = t + 256 * i;     // 1024 float4 = 32 rows x 32 float4
            const int row = f >> 5;
            const int c4 = f & 31;
            *reinterpret_cast<float4*>(&tile[row][c4 * 2]) = src[f];
        }
        __syncthreads();
#pragma unroll 2
        for (int r = 0; r < GR_TROWS; ++r) {
            float2 xa[4], xb[4];
#pragma unroll
            for (int a = 0; a < 4; ++a) xa[a] = tile[r][j1 + 16 * a];
#pragma unroll
            for (int b = 0; b < 4; ++b) xb[b] = tile[r][k1 + 16 * b];
            // Cholesky only reads the upper triangle of G: skip groups a > b.
#pragma unroll
            for (int a = 0; a < 4; ++a)
#pragma unroll
                for (int b = 0; b < 4; ++b)
                    if (a <= b) cmac_conj(acc[a][b], xa[a], xb[b]);
        }
        __syncthreads();
    }
    float* G = Gbufs + (size_t)(blockIdx.x & bufmask) * 8192;
#pragma unroll
    for (int a = 0; a < 4; ++a)
#pragma unroll
        for (int b = 0; b < 4; ++b)
            if (a <= b) {
                const int idx = (j1 + 16 * a) * NCOL + (k1 + 16 * b);
                atomicAdd(&G[2 * idx], acc[a][b].x);
                atomicAdd(&G[2 * idx + 1], acc[a][b].y);
            }
}

// ---------------- single-wave register cholinv: reduce + Cholesky + R^{-1} ----------------
// Lane k holds column k of A in registers (128 VGPR). __launch_bounds__(64, 1)
// gives the 1-wave/SIMD VGPR budget (512) so a[64] does NOT spill (R3 failure
// mode: default occupancy target capped at 132 VGPR -> scratch round-trips).
// Broadcasts via v_readlane (SGPR, no memory ordering). Zero barriers in the
// factorization; ~2 barriers total.
__global__ __launch_bounds__(64, 1) void cholinv_kernel(const float* __restrict__ Gbufs, int nbuf,
                                                        float2* __restrict__ RinvOut) {
    __shared__ float2 R[64 * 64];   // row i = R[i][:] after phase 3; diag packs {d, dinv}
    const int k = threadIdx.x;      // lane = column

    // 1) reduce partial G buffers into LDS
    {
        float4* R4 = reinterpret_cast<float4*>(R);
        const float4* Gb4 = reinterpret_cast<const float4*>(Gbufs);
        for (int it = 0; it < 32; ++it) {
            const int f = k + 64 * it;      // 2048 float4
            float4 s = Gb4[f];
            for (int b = 1; b < nbuf; ++b) {
                const float4 u = Gb4[b * 2048 + f];
                s.x += u.x; s.y += u.y; s.z += u.z; s.w += u.w;
            }
            R4[f] = s;
        }
    }
    __syncthreads();

    // 2) lane k <- column k of G (lower-triangle entries unused/garbage-tolerant)
    float2 a[64];
#pragma unroll
    for (int j = 0; j < 64; ++j) a[j] = R[j * 64 + k];

    // 3) Cholesky, fully unrolled, zero barriers. Row i of R -> LDS.
#pragma unroll
    for (int i = 0; i < 64; ++i) {
        const float dsq = lane_bcast(a[i].x, i);
        const float d = sqrtf(fmaxf(dsq, 1e-30f));
        const float dinv = 1.0f / d;
        float2 rr;                       // R[i][k] in lane k (valid for k >= i)
        rr.x = a[i].x * dinv;
        rr.y = a[i].y * dinv;
        if (k == i) { rr.x = d; rr.y = 0.f; }
        float2 st = rr;
        if (k == i) st.y = dinv;         // pack dinv into diag imag slot
        R[i * 64 + k] = st;
#pragma unroll
        for (int j = i + 1; j < 64; ++j) {
            const float rijx = lane_bcast(rr.x, j);
            const float rijy = lane_bcast(rr.y, j);
            // a[j] -= conj(rij) * rr
            a[j].x = fmaf(-rijx, rr.x, fmaf(-rijy, rr.y, a[j].x));
            a[j].y = fmaf(-rijx, rr.y, fmaf( rijy, rr.x, a[j].y));
        }
    }
    __syncthreads();

    // 4) lane k <- column k of Rinv (reuse a[]); self-masking recurrence:
    //    a[j] = W[j][k], zero for j > k, so lower triangle stays exactly 0.
    const float dk = R[k * 64 + k].y;
#pragma unroll
    for (int j = 0; j < 64; ++j)
        a[j] = (j == k) ? make_float2(dk, 0.f) : make_float2(0.f, 0.f);
#pragma unroll
    for (int ii = 0; ii < 63; ++ii) {
        const int i = 62 - ii;
        float2 s = make_float2(0.f, 0.f);
#pragma unroll
        for (int j = i + 1; j < 64; ++j) {
            const float2 rij = R[i * 64 + j];   // uniform broadcast read
            s.x = fmaf(rij.x, a[j].x, fmaf(-rij.y, a[j].y, s.x));
            s.y = fmaf(rij.x, a[j].y, fmaf( rij.y, a[j].x, s.y));
        }
        const float di = R[i * 64 + i].y;       // dinv_i
        if (k != i) { a[i].x = -di * s.x; a[i].y = -di * s.y; }
    }

    // 5) write Rinv (exact zeros below diagonal)
#pragma unroll
    for (int i = 0; i < 64; ++i) RinvOut[i * 64 + k] = a[i];
}

// ---------------- Q = X * Rinv (triangular j-loop) ----------------
#define AP_BLOCKS 2048
#define AP_ROWS (M_ROWS / AP_BLOCKS)   // 128
#define AP_TROWS 32

__global__ __launch_bounds__(256) void apply_kernel(const float4* __restrict__ X4,
                                                    const float4* __restrict__ Rinv4,
                                                    float2* __restrict__ Q2) {
    __shared__ float2 W[64][64];
    __shared__ float2 tile[AP_TROWS][66];
    const int t = threadIdx.x;
#pragma unroll
    for (int i = 0; i < 8; ++i) {
        const int f = t + 256 * i;
        reinterpret_cast<float4*>(&W[0][0])[f] = Rinv4[f];
    }
    const int k1 = t & 15;
    const int r1 = t >> 4;
    const int rbeg = blockIdx.x * AP_ROWS;
    for (int t0 = 0; t0 < AP_ROWS; t0 += AP_TROWS) {
        const float4* src = X4 + (size_t)(rbeg + t0) * (NCOL / 2);
#pragma unroll
        for (int i = 0; i < 4; ++i) {
            const int f = t + 256 * i;
            const int row = f >> 5;
            const int c4 = f & 31;
            *reinterpret_cast<float4*>(&tile[row][c4 * 2]) = src[f];
        }
        __syncthreads();
        float2 acc[2][4];
#pragma unroll
        for (int a = 0; a < 2; ++a)
#pragma unroll
            for (int b = 0; b < 4; ++b) acc[a][b] = make_float2(0.f, 0.f);

#define SEG(JLO, JHI, BMIN)                                          \
        _Pragma("unroll 2")                                          \
        for (int j = (JLO); j < (JHI); ++j) {                        \
            const float2 x0 = tile[r1][j];                           \
            const float2 x1 = tile[r1 + 16][j];                      \
            _Pragma("unroll")                                        \
            for (int b = (BMIN); b < 4; ++b) {                       \
                const float2 w = W[j][k1 + 16 * b];                  \
                cmac(acc[0][b], x0, w);                              \
                cmac(acc[1][b], x1, w);                              \
            }                                                        \
        }
        SEG(0, 16, 0)
        SEG(16, 32, 1)
        SEG(32, 48, 2)
        SEG(48, 64, 3)
#undef SEG

#pragma unroll
        for (int a = 0; a < 2; ++a) {
            const size_t row = (size_t)(rbeg + t0 + r1 + 16 * a);
#pragma unroll
            for (int b = 0; b < 4; ++b) Q2[row * NCOL + k1 + 16 * b] = acc[a][b];
        }
        __syncthreads();
    }
}

extern "C" void kernel_launch(void* const* d_in, const int* in_sizes, int n_in,
                              void* d_out, int out_size, void* d_ws, size_t ws_size,
                              hipStream_t stream) {
    (void)in_sizes; (void)n_in; (void)out_size;
    const float4* X4 = reinterpret_cast<const float4*>(d_in[0]);
    float* Gbufs = reinterpret_cast<float*>(d_ws);
    int nbuf = 1;
    while (nbuf < 16 && (size_t)(2 * nbuf) * 32768 + 32768 <= ws_size) nbuf <<= 1;
    float2* Rinv = reinterpret_cast<float2*>((char*)d_ws + (size_t)nbuf * 32768);

    hipMemsetAsync(Gbufs, 0, (size_t)nbuf * 32768, stream);
    gram_kernel<<<GR_BLOCKS, 256, 0, stream>>>(X4, Gbufs, nbuf - 1);
    cholinv_kernel<<<1, 64, 0, stream>>>(Gbufs, nbuf, Rinv);
    apply_kernel<<<AP_BLOCKS, 256, 0, stream>>>(X4, reinterpret_cast<const float4*>(Rinv),
                                                reinterpret_cast<float2*>(d_out));
}

// Round 6
// 316.841 us; speedup vs baseline: 1.7575x; 1.3478x over previous
//
#include <hip/hip_runtime.h>
#include <math.h>

#define NCOL 64
#define M_ROWS 262144

__device__ __forceinline__ void cmac_conj(float2& acc, const float2 a, const float2 b) {
    // acc += conj(a) * b
    acc.x = fmaf(a.x, b.x, acc.x);
    acc.x = fmaf(a.y, b.y, acc.x);
    acc.y = fmaf(a.x, b.y, acc.y);
    acc.y = fmaf(-a.y, b.x, acc.y);
}
__device__ __forceinline__ void cmac(float2& acc, const float2 a, const float2 b) {
    // acc += a * b
    acc.x = fmaf(a.x, b.x, acc.x);
    acc.x = fmaf(-a.y, b.y, acc.x);
    acc.y = fmaf(a.x, b.y, acc.y);
    acc.y = fmaf(a.y, b.x, acc.y);
}
__device__ __forceinline__ float lane_bcast(float v, int lane) {
    return __uint_as_float(__builtin_amdgcn_readlane(__float_as_uint(v), lane));
}

// ---------------- G = X^H X, upper-triangle groups only ----------------
#define GR_BLOCKS 2048
#define GR_ROWS (M_ROWS / GR_BLOCKS)   // 128
#define GR_TROWS 32

__global__ __launch_bounds__(256) void gram_kernel(const float4* __restrict__ X4,
                                                   float* __restrict__ Gbufs, int bufmask) {
    __shared__ float2 tile[GR_TROWS][66];
    const int t = threadIdx.x;
    const int j1 = t >> 4;   // G rows j1+{0,16,32,48}
    const int k1 = t & 15;   // G cols k1+{0,16,32,48}
    float2 acc[4][4];
#pragma unroll
    for (int a = 0; a < 4; ++a)
#pragma unroll
        for (int b = 0; b < 4; ++b) acc[a][b] = make_float2(0.f, 0.f);

    const int rbeg = blockIdx.x * GR_ROWS;
    for (int t0 = 0; t0 < GR_ROWS; t0 += GR_TROWS) {
        const float4* src = X4 + (size_t)(rbeg + t0) * (NCOL / 2);
#pragma unroll
        for (int i = 0; i < 4; ++i) {
            const int f = t + 256 * i;     // 1024 float4 = 32 rows x 32 float4
            const int row = f >> 5;
            const int c4 = f & 31;
            *reinterpret_cast<float4*>(&tile[row][c4 * 2]) = src[f];
        }
        __syncthreads();
#pragma unroll 2
        for (int r = 0; r < GR_TROWS; ++r) {
            float2 xa[4], xb[4];
#pragma unroll
            for (int a = 0; a < 4; ++a) xa[a] = tile[r][j1 + 16 * a];
#pragma unroll
            for (int b = 0; b < 4; ++b) xb[b] = tile[r][k1 + 16 * b];
            // Cholesky only reads the upper triangle of G: skip groups a > b.
#pragma unroll
            for (int a = 0; a < 4; ++a)
#pragma unroll
                for (int b = 0; b < 4; ++b)
                    if (a <= b) cmac_conj(acc[a][b], xa[a], xb[b]);
        }
        __syncthreads();
    }
    float* G = Gbufs + (size_t)(blockIdx.x & bufmask) * 8192;
#pragma unroll
    for (int a = 0; a < 4; ++a)
#pragma unroll
        for (int b = 0; b < 4; ++b)
            if (a <= b) {
                const int idx = (j1 + 16 * a) * NCOL + (k1 + 16 * b);
                atomicAdd(&G[2 * idx], acc[a][b].x);
                atomicAdd(&G[2 * idx + 1], acc[a][b].y);
            }
}

// ---------------- parallel reduction of the nbuf partial G buffers ----------------
// R5 lesson: doing this inside the single-wave cholinv = ~512 serialized global
// loads (runtime-bound loop, vmcnt-waited) ~ 150+ us. 2048 threads hide it all.
__global__ __launch_bounds__(256) void reduce_kernel(const float* __restrict__ Gbufs, int nbuf,
                                                     float* __restrict__ Gfinal) {
    const int f = blockIdx.x * 256 + threadIdx.x;   // 2048 float4 = 64x64 float2
    const float4* Gb4 = reinterpret_cast<const float4*>(Gbufs);
    float4 s = Gb4[f];
    for (int b = 1; b < nbuf; ++b) {
        const float4 u = Gb4[b * 2048 + f];
        s.x += u.x; s.y += u.y; s.z += u.z; s.w += u.w;
    }
    reinterpret_cast<float4*>(Gfinal)[f] = s;
}

// ---------------- single-wave register cholinv: Cholesky + R^{-1} ----------------
// Lane k holds column k of A in registers. Broadcasts via v_readlane (SGPR, no
// memory ordering). Zero barriers in the factorization.
__global__ __launch_bounds__(64, 1) void cholinv_kernel(const float* __restrict__ Gfinal,
                                                        float2* __restrict__ RinvOut) {
    __shared__ float2 R[64 * 64];   // row i = R[i][:] after phase 3; diag packs {d, dinv}
    const int k = threadIdx.x;      // lane = column

    // 1) stage reduced G into LDS (32 independent float4 loads/lane, pipelined)
    {
        float4* R4 = reinterpret_cast<float4*>(R);
        const float4* G4 = reinterpret_cast<const float4*>(Gfinal);
#pragma unroll
        for (int it = 0; it < 32; ++it) {
            const int f = k + 64 * it;      // 2048 float4
            R4[f] = G4[f];
        }
    }
    __syncthreads();

    // 2) lane k <- column k of G (lower-triangle entries unused/garbage-tolerant)
    float2 a[64];
#pragma unroll
    for (int j = 0; j < 64; ++j) a[j] = R[j * 64 + k];

    // 3) Cholesky, fully unrolled, zero barriers. Row i of R -> LDS.
#pragma unroll
    for (int i = 0; i < 64; ++i) {
        const float dsq = lane_bcast(a[i].x, i);
        const float d = sqrtf(fmaxf(dsq, 1e-30f));
        const float dinv = 1.0f / d;
        float2 rr;                       // R[i][k] in lane k (valid for k >= i)
        rr.x = a[i].x * dinv;
        rr.y = a[i].y * dinv;
        if (k == i) { rr.x = d; rr.y = 0.f; }
        float2 st = rr;
        if (k == i) st.y = dinv;         // pack dinv into diag imag slot
        R[i * 64 + k] = st;
#pragma unroll
        for (int j = i + 1; j < 64; ++j) {
            const float rijx = lane_bcast(rr.x, j);
            const float rijy = lane_bcast(rr.y, j);
            // a[j] -= conj(rij) * rr
            a[j].x = fmaf(-rijx, rr.x, fmaf(-rijy, rr.y, a[j].x));
            a[j].y = fmaf(-rijx, rr.y, fmaf( rijy, rr.x, a[j].y));
        }
    }
    __syncthreads();

    // 4) lane k <- column k of Rinv (reuse a[]); self-masking recurrence:
    //    a[j] = W[j][k], zero for j > k, so lower triangle stays exactly 0.
    const float dk = R[k * 64 + k].y;
#pragma unroll
    for (int j = 0; j < 64; ++j)
        a[j] = (j == k) ? make_float2(dk, 0.f) : make_float2(0.f, 0.f);
#pragma unroll
    for (int ii = 0; ii < 63; ++ii) {
        const int i = 62 - ii;
        float2 s = make_float2(0.f, 0.f);
#pragma unroll
        for (int j = i + 1; j < 64; ++j) {
            const float2 rij = R[i * 64 + j];   // uniform broadcast read
            s.x = fmaf(rij.x, a[j].x, fmaf(-rij.y, a[j].y, s.x));
            s.y = fmaf(rij.x, a[j].y, fmaf( rij.y, a[j].x, s.y));
        }
        const float di = R[i * 64 + i].y;       // dinv_i
        if (k != i) { a[i].x = -di * s.x; a[i].y = -di * s.y; }
    }

    // 5) write Rinv (exact zeros below diagonal)
#pragma unroll
    for (int i = 0; i < 64; ++i) RinvOut[i * 64 + k] = a[i];
}

// ---------------- Q = X * Rinv (triangular j-loop) ----------------
#define AP_BLOCKS 2048
#define AP_ROWS (M_ROWS / AP_BLOCKS)   // 128
#define AP_TROWS 32

__global__ __launch_bounds__(256) void apply_kernel(const float4* __restrict__ X4,
                                                    const float4* __restrict__ Rinv4,
                                                    float2* __restrict__ Q2) {
    __shared__ float2 W[64][64];
    __shared__ float2 tile[AP_TROWS][66];
    const int t = threadIdx.x;
#pragma unroll
    for (int i = 0; i < 8; ++i) {
        const int f = t + 256 * i;
        reinterpret_cast<float4*>(&W[0][0])[f] = Rinv4[f];
    }
    const int k1 = t & 15;
    const int r1 = t >> 4;
    const int rbeg = blockIdx.x * AP_ROWS;
    for (int t0 = 0; t0 < AP_ROWS; t0 += AP_TROWS) {
        const float4* src = X4 + (size_t)(rbeg + t0) * (NCOL / 2);
#pragma unroll
        for (int i = 0; i < 4; ++i) {
            const int f = t + 256 * i;
            const int row = f >> 5;
            const int c4 = f & 31;
            *reinterpret_cast<float4*>(&tile[row][c4 * 2]) = src[f];
        }
        __syncthreads();
        float2 acc[2][4];
#pragma unroll
        for (int a = 0; a < 2; ++a)
#pragma unroll
            for (int b = 0; b < 4; ++b) acc[a][b] = make_float2(0.f, 0.f);

#define SEG(JLO, JHI, BMIN)                                          \
        _Pragma("unroll 2")                                          \
        for (int j = (JLO); j < (JHI); ++j) {                        \
            const float2 x0 = tile[r1][j];                           \
            const float2 x1 = tile[r1 + 16][j];                      \
            _Pragma("unroll")                                        \
            for (int b = (BMIN); b < 4; ++b) {                       \
                const float2 w = W[j][k1 + 16 * b];                  \
                cmac(acc[0][b], x0, w);                              \
                cmac(acc[1][b], x1, w);                              \
            }                                                        \
        }
        SEG(0, 16, 0)
        SEG(16, 32, 1)
        SEG(32, 48, 2)
        SEG(48, 64, 3)
#undef SEG

#pragma unroll
        for (int a = 0; a < 2; ++a) {
            const size_t row = (size_t)(rbeg + t0 + r1 + 16 * a);
#pragma unroll
            for (int b = 0; b < 4; ++b) Q2[row * NCOL + k1 + 16 * b] = acc[a][b];
        }
        __syncthreads();
    }
}

extern "C" void kernel_launch(void* const* d_in, const int* in_sizes, int n_in,
                              void* d_out, int out_size, void* d_ws, size_t ws_size,
                              hipStream_t stream) {
    (void)in_sizes; (void)n_in; (void)out_size;
    const float4* X4 = reinterpret_cast<const float4*>(d_in[0]);
    float* Gbufs = reinterpret_cast<float*>(d_ws);
    int nbuf = 1;
    while (nbuf < 16 && (size_t)(2 * nbuf) * 32768 + 65536 <= ws_size) nbuf <<= 1;
    float2* Rinv = reinterpret_cast<float2*>((char*)d_ws + (size_t)nbuf * 32768);
    float* Gfinal = reinterpret_cast<float*>((char*)d_ws + (size_t)nbuf * 32768 + 32768);

    hipMemsetAsync(Gbufs, 0, (size_t)nbuf * 32768, stream);
    gram_kernel<<<GR_BLOCKS, 256, 0, stream>>>(X4, Gbufs, nbuf - 1);
    reduce_kernel<<<8, 256, 0, stream>>>(Gbufs, nbuf, Gfinal);
    cholinv_kernel<<<1, 64, 0, stream>>>(Gfinal, Rinv);
    apply_kernel<<<AP_BLOCKS, 256, 0, stream>>>(X4, reinterpret_cast<const float4*>(Rinv),
                                                reinterpret_cast<float2*>(d_out));
}

// Round 7
// 236.654 us; speedup vs baseline: 2.3530x; 1.3388x over previous
//
#include <hip/hip_runtime.h>
#include <math.h>

#define NCOL 64
#define M_ROWS 262144

typedef short bf16x8 __attribute__((ext_vector_type(8)));
typedef float f32x4 __attribute__((ext_vector_type(4)));

__device__ __forceinline__ unsigned short f2bf(float f) {  // RNE fp32->bf16
    unsigned int u = __float_as_uint(f);
    u += 0x7FFFu + ((u >> 16) & 1u);
    return (unsigned short)(u >> 16);
}
__device__ __forceinline__ float bf2f(unsigned short s) {
    return __uint_as_float(((unsigned int)s) << 16);
}
__device__ __forceinline__ void cmac(float2& acc, const float2 a, const float2 b) {
    acc.x = fmaf(a.x, b.x, acc.x);
    acc.x = fmaf(-a.y, b.y, acc.x);
    acc.y = fmaf(a.x, b.y, acc.y);
    acc.y = fmaf(a.y, b.x, acc.y);
}
__device__ __forceinline__ float lane_bcast(float v, int lane) {
    return __uint_as_float(__builtin_amdgcn_readlane(__float_as_uint(v), lane));
}

// ---------------- S = Y^T Y via MFMA on the interleaved real M x 128 view ----------------
// Per-lane strided global gathers (L3-resident X, full 64B-line use), no LDS, no barriers.
// frag[kt]: lane l holds Y[m0 + (l>>4)*8 + i][16*kt + (l&15)] as bf16 — serves as BOTH the
// A-frag (for tile-row 16*kt) and B-frag (for tile-col 16*kt); k-mapping identical for A/B
// so any internal k-permutation cancels. S is symmetric -> A/B-swap and C-transpose harmless.
#define GR_BLOCKS 512
#define GR_KTILES (M_ROWS / 32 / GR_BLOCKS)  // 16

__global__ __launch_bounds__(256) void gram_mfma(const float* __restrict__ X,
                                                 float* __restrict__ Sbufs, int bufmask) {
    const int t = threadIdx.x;
    const int w = t >> 6, l = t & 63, r = l & 15, c = l >> 4;
    const float* p = X + (size_t)(blockIdx.x * (GR_KTILES * 32) + c * 8) * 128 + r;
    f32x4 acc[2][8];
#pragma unroll
    for (int jr = 0; jr < 2; ++jr)
#pragma unroll
        for (int kt = 0; kt < 8; ++kt) acc[jr][kt] = (f32x4){0.f, 0.f, 0.f, 0.f};

    for (int tt = 0; tt < GR_KTILES; ++tt) {
        bf16x8 frag[8];
#pragma unroll
        for (int kt = 0; kt < 8; ++kt) {
            float x[8];
#pragma unroll
            for (int i = 0; i < 8; ++i) x[i] = p[i * 128 + kt * 16];  // imm offsets <= 4032B
#pragma unroll
            for (int i = 0; i < 8; ++i) frag[kt][i] = (short)f2bf(x[i]);
        }
        // wave w owns tile-rows 2w, 2w+1; uniform branch keeps all frag indices constant (rule #20)
#pragma unroll
        for (int s = 0; s < 8; ++s) {
            if ((s >> 1) == w) {
#pragma unroll
                for (int kt = 0; kt < 8; ++kt)
                    acc[s & 1][kt] = __builtin_amdgcn_mfma_f32_16x16x32_bf16(
                        frag[s], frag[kt], acc[s & 1][kt], 0, 0, 0);
            }
        }
        p += 32 * 128;
    }
    float* Sb = Sbufs + (size_t)(blockIdx.x & bufmask) * 16384;
#pragma unroll
    for (int jr = 0; jr < 2; ++jr)
#pragma unroll
        for (int kt = 0; kt < 8; ++kt)
#pragma unroll
            for (int q = 0; q < 4; ++q)
                atomicAdd(&Sb[(32 * w + 16 * jr + 4 * c + q) * 128 + 16 * kt + r],
                          acc[jr][kt][q]);
}

// ---------------- reduce replicas + map real S(128x128) -> complex G(64x64) ----------------
__global__ __launch_bounds__(256) void reduce_g(const float* __restrict__ Sbufs, int nbuf,
                                                float2* __restrict__ Gc) {
    const int idx = blockIdx.x * 256 + threadIdx.x;  // 4096
    const int j = idx >> 6, k = idx & 63;
    float s00 = 0.f, s01 = 0.f, s10 = 0.f, s11 = 0.f;
    for (int b = 0; b < nbuf; ++b) {
        const float* S = Sbufs + (size_t)b * 16384;
        s00 += S[(2 * j) * 128 + 2 * k];
        s01 += S[(2 * j) * 128 + 2 * k + 1];
        s10 += S[(2 * j + 1) * 128 + 2 * k];
        s11 += S[(2 * j + 1) * 128 + 2 * k + 1];
    }
    Gc[idx] = make_float2(s00 + s11, s01 - s10);
}

// ---------------- single-wave register cholinv + W2t(bf16 h/l) emit ----------------
// Lane k holds column k in registers; readlane broadcasts; ~2 barriers total.
// Epilogue writes the transposed real 128x128 form of W=R^{-1}, split bf16 hi/lo:
//   W2t[2k][2j]=wr  W2t[2k][2j+1]=-wi  W2t[2k+1][2j]=wi  W2t[2k+1][2j+1]=wr
__global__ __launch_bounds__(64, 1) void cholinv_kernel(const float2* __restrict__ Gc,
                                                        unsigned int* __restrict__ W2h,
                                                        unsigned int* __restrict__ W2l) {
    __shared__ float2 R[64 * 64];
    const int k = threadIdx.x;
    {
        float4* R4 = reinterpret_cast<float4*>(R);
        const float4* G4 = reinterpret_cast<const float4*>(Gc);
#pragma unroll
        for (int it = 0; it < 32; ++it) R4[k + 64 * it] = G4[k + 64 * it];
    }
    __syncthreads();

    float2 a[64];
#pragma unroll
    for (int j = 0; j < 64; ++j) a[j] = R[j * 64 + k];

#pragma unroll
    for (int i = 0; i < 64; ++i) {
        const float dsq = lane_bcast(a[i].x, i);
        const float d = sqrtf(fmaxf(dsq, 1e-30f));
        const float dinv = 1.0f / d;
        float2 rr;
        rr.x = a[i].x * dinv;
        rr.y = a[i].y * dinv;
        if (k == i) { rr.x = d; rr.y = 0.f; }
        float2 st = rr;
        if (k == i) st.y = dinv;
        R[i * 64 + k] = st;
#pragma unroll
        for (int j = i + 1; j < 64; ++j) {
            const float rijx = lane_bcast(rr.x, j);
            const float rijy = lane_bcast(rr.y, j);
            a[j].x = fmaf(-rijx, rr.x, fmaf(-rijy, rr.y, a[j].x));
            a[j].y = fmaf(-rijx, rr.y, fmaf( rijy, rr.x, a[j].y));
        }
    }
    __syncthreads();

    const float dk = R[k * 64 + k].y;
#pragma unroll
    for (int j = 0; j < 64; ++j)
        a[j] = (j == k) ? make_float2(dk, 0.f) : make_float2(0.f, 0.f);
#pragma unroll
    for (int ii = 0; ii < 63; ++ii) {
        const int i = 62 - ii;
        float2 s = make_float2(0.f, 0.f);
#pragma unroll
        for (int j = i + 1; j < 64; ++j) {
            const float2 rij = R[i * 64 + j];
            s.x = fmaf(rij.x, a[j].x, fmaf(-rij.y, a[j].y, s.x));
            s.y = fmaf(rij.x, a[j].y, fmaf( rij.y, a[j].x, s.y));
        }
        const float di = R[i * 64 + i].y;
        if (k != i) { a[i].x = -di * s.x; a[i].y = -di * s.y; }
    }

    // a[j] = W[j][k], exact zeros for j>k, a[k]=(dinv_k,0). Emit W2t rows 2k, 2k+1.
    const unsigned int row0 = (unsigned int)(2 * k) * 64;
    const unsigned int row1 = row0 + 64;
#pragma unroll
    for (int j = 0; j < 64; ++j) {
        const float wr = a[j].x, wi = a[j].y;
        const unsigned short wr_h = f2bf(wr);
        const unsigned short wr_l = f2bf(wr - bf2f(wr_h));
        const unsigned short wi_h = f2bf(wi);
        const unsigned short wi_l = f2bf(wi - bf2f(wi_h));
        const unsigned short nwi_h = f2bf(-wi);
        const unsigned short nwi_l = f2bf(-wi - bf2f(nwi_h));
        W2h[row0 + j] = (unsigned int)wr_h | ((unsigned int)nwi_h << 16);
        W2l[row0 + j] = (unsigned int)wr_l | ((unsigned int)nwi_l << 16);
        W2h[row1 + j] = (unsigned int)wi_h | ((unsigned int)wr_h << 16);
        W2l[row1 + j] = (unsigned int)wi_l | ((unsigned int)wr_l << 16);
    }
}

// ---------------- Q = Y * W2t via MFMA, W-frags hoisted to VGPRs, no LDS ----------------
// Split both operands: Q = Xh*Wh + Xh*Wl + Xl*Wh (dropped Xl*Wl ~ 1e-8).
#define AP_BLOCKS 1024
#define AP_RTILES (M_ROWS / 16 / AP_BLOCKS)  // 16

__global__ __launch_bounds__(256) void apply_mfma(const float* __restrict__ X,
                                                  const unsigned short* __restrict__ W2h,
                                                  const unsigned short* __restrict__ W2l,
                                                  float* __restrict__ Q) {
    const int t = threadIdx.x;
    const int w = t >> 6, l = t & 63, r = l & 15, c = l >> 4;

    // hoist B-frags once per block: wave w owns output cols 32w..32w+31 (2 tiles x 4 k-chunks)
    bf16x8 bh[2][4], bl[2][4];
#pragma unroll
    for (int ct = 0; ct < 2; ++ct)
#pragma unroll
        for (int kc = 0; kc < 4; ++kc) {
            const int idx = (32 * w + 16 * ct + r) * 128 + kc * 32 + c * 8;
            bh[ct][kc] = *reinterpret_cast<const bf16x8*>(W2h + idx);
            bl[ct][kc] = *reinterpret_cast<const bf16x8*>(W2l + idx);
        }

    const size_t m0 = (size_t)blockIdx.x * (AP_RTILES * 16);
    const float* p = X + (m0 + r) * 128 + c * 8;
    float* qp = Q + (m0 + 4 * c) * 128 + 32 * w + r;

    for (int tt = 0; tt < AP_RTILES; ++tt) {
        bf16x8 ah[4], al[4];
#pragma unroll
        for (int kc = 0; kc < 4; ++kc) {
            const float4 v0 = *reinterpret_cast<const float4*>(p + kc * 32);
            const float4 v1 = *reinterpret_cast<const float4*>(p + kc * 32 + 4);
            const float x[8] = {v0.x, v0.y, v0.z, v0.w, v1.x, v1.y, v1.z, v1.w};
#pragma unroll
            for (int i = 0; i < 8; ++i) {
                const unsigned short h = f2bf(x[i]);
                ah[kc][i] = (short)h;
                al[kc][i] = (short)f2bf(x[i] - bf2f(h));
            }
        }
        f32x4 acc[2];
        acc[0] = (f32x4){0.f, 0.f, 0.f, 0.f};
        acc[1] = (f32x4){0.f, 0.f, 0.f, 0.f};
#pragma unroll
        for (int kc = 0; kc < 4; ++kc)
#pragma unroll
            for (int ct = 0; ct < 2; ++ct) {
                acc[ct] = __builtin_amdgcn_mfma_f32_16x16x32_bf16(ah[kc], bh[ct][kc], acc[ct], 0, 0, 0);
                acc[ct] = __builtin_amdgcn_mfma_f32_16x16x32_bf16(ah[kc], bl[ct][kc], acc[ct], 0, 0, 0);
                acc[ct] = __builtin_amdgcn_mfma_f32_16x16x32_bf16(al[kc], bh[ct][kc], acc[ct], 0, 0, 0);
            }
        // D: col = lane&15, row = (lane>>4)*4 + reg  [m89/m91]
#pragma unroll
        for (int ct = 0; ct < 2; ++ct)
#pragma unroll
            for (int q = 0; q < 4; ++q)
                qp[q * 128 + ct * 16] = acc[ct][q];
        p += 16 * 128;
        qp += 16 * 128;
    }
}

extern "C" void kernel_launch(void* const* d_in, const int* in_sizes, int n_in,
                              void* d_out, int out_size, void* d_ws, size_t ws_size,
                              hipStream_t stream) {
    (void)in_sizes; (void)n_in; (void)out_size;
    const float* X = reinterpret_cast<const float*>(d_in[0]);
    float* Q = reinterpret_cast<float*>(d_out);

    const size_t extra = 98304;  // Gc 32K + W2h 32K + W2l 32K
    int nbuf = 1;
    while (nbuf < 16 && (size_t)(nbuf * 2) * 65536 + extra <= ws_size) nbuf <<= 1;
    float* Sbufs = reinterpret_cast<float*>(d_ws);
    char* pextra = (char*)d_ws + (size_t)nbuf * 65536;
    float2* Gc = reinterpret_cast<float2*>(pextra);
    unsigned int* W2h = reinterpret_cast<unsigned int*>(pextra + 32768);
    unsigned int* W2l = reinterpret_cast<unsigned int*>(pextra + 65536);

    hipMemsetAsync(Sbufs, 0, (size_t)nbuf * 65536, stream);
    gram_mfma<<<GR_BLOCKS, 256, 0, stream>>>(X, Sbufs, nbuf - 1);
    reduce_g<<<16, 256, 0, stream>>>(Sbufs, nbuf, Gc);
    cholinv_kernel<<<1, 64, 0, stream>>>(Gc, W2h, W2l);
    apply_mfma<<<AP_BLOCKS, 256, 0, stream>>>(X, reinterpret_cast<const unsigned short*>(W2h),
                                              reinterpret_cast<const unsigned short*>(W2l), Q);
}

// Round 8
// 216.683 us; speedup vs baseline: 2.5699x; 1.0922x over previous
//
#include <hip/hip_runtime.h>
#include <math.h>

#define NCOL 64
#define M_ROWS 262144

typedef short bf16x8 __attribute__((ext_vector_type(8)));
typedef float f32x4 __attribute__((ext_vector_type(4)));

__device__ __forceinline__ unsigned short f2bf(float f) {  // RNE fp32->bf16
    unsigned int u = __float_as_uint(f);
    u += 0x7FFFu + ((u >> 16) & 1u);
    return (unsigned short)(u >> 16);
}
__device__ __forceinline__ float bf2f(unsigned short s) {
    return __uint_as_float(((unsigned int)s) << 16);
}
__device__ __forceinline__ float lane_bcast(float v, int lane) {
    return __uint_as_float(__builtin_amdgcn_readlane(__float_as_uint(v), lane));
}

// ---------------- S = Y^T Y via MFMA on the interleaved real M x 128 view ----------------
#define GR_BLOCKS 512
#define GR_KTILES (M_ROWS / 32 / GR_BLOCKS)  // 16

__global__ __launch_bounds__(256) void gram_mfma(const float* __restrict__ X,
                                                 float* __restrict__ Sbufs, int bufmask) {
    const int t = threadIdx.x;
    const int w = t >> 6, l = t & 63, r = l & 15, c = l >> 4;
    const float* p = X + (size_t)(blockIdx.x * (GR_KTILES * 32) + c * 8) * 128 + r;
    f32x4 acc[2][8];
#pragma unroll
    for (int jr = 0; jr < 2; ++jr)
#pragma unroll
        for (int kt = 0; kt < 8; ++kt) acc[jr][kt] = (f32x4){0.f, 0.f, 0.f, 0.f};

    for (int tt = 0; tt < GR_KTILES; ++tt) {
        bf16x8 frag[8];
#pragma unroll
        for (int kt = 0; kt < 8; ++kt) {
            float x[8];
#pragma unroll
            for (int i = 0; i < 8; ++i) x[i] = p[i * 128 + kt * 16];
#pragma unroll
            for (int i = 0; i < 8; ++i) frag[kt][i] = (short)f2bf(x[i]);
        }
#pragma unroll
        for (int s = 0; s < 8; ++s) {
            if ((s >> 1) == w) {
#pragma unroll
                for (int kt = 0; kt < 8; ++kt)
                    acc[s & 1][kt] = __builtin_amdgcn_mfma_f32_16x16x32_bf16(
                        frag[s], frag[kt], acc[s & 1][kt], 0, 0, 0);
            }
        }
        p += 32 * 128;
    }
    float* Sb = Sbufs + (size_t)(blockIdx.x & bufmask) * 16384;
#pragma unroll
    for (int jr = 0; jr < 2; ++jr)
#pragma unroll
        for (int kt = 0; kt < 8; ++kt)
#pragma unroll
            for (int q = 0; q < 4; ++q)
                atomicAdd(&Sb[(32 * w + 16 * jr + 4 * c + q) * 128 + 16 * kt + r],
                          acc[jr][kt][q]);
}

// ---------------- reduce replicas + map real S(128x128) -> complex G(64x64) ----------------
__global__ __launch_bounds__(256) void reduce_g(const float* __restrict__ Sbufs, int nbuf,
                                                float2* __restrict__ Gc) {
    const int idx = blockIdx.x * 256 + threadIdx.x;  // 4096
    const int j = idx >> 6, k = idx & 63;
    float s00 = 0.f, s01 = 0.f, s10 = 0.f, s11 = 0.f;
    for (int b = 0; b < nbuf; ++b) {
        const float* S = Sbufs + (size_t)b * 16384;
        s00 += S[(2 * j) * 128 + 2 * k];
        s01 += S[(2 * j) * 128 + 2 * k + 1];
        s10 += S[(2 * j + 1) * 128 + 2 * k];
        s11 += S[(2 * j + 1) * 128 + 2 * k + 1];
    }
    Gc[idx] = make_float2(s00 + s11, s01 - s10);
}

// ---------------- 4-wave rolled cholinv: small code (icache-resident), LDS state ----------------
// Phase 1: Cholesky, one barrier/step; all waves redundantly compute the pivot from a
// per-lane row read; trailing rows j split across waves (j = i+1+w step 4). Finalized
// R rows -> Rr (diag packs {d,dinv}); A keeps the raw Schur complement.
// Phase 2: W = R^{-1} blocked: waves 0,1 invert the 32x32 diagonal blocks independently
// (column-per-lane, rolled back-substitution); then W12 = -W11*(R12*W22) as two 32x32
// complex GEMMs on all 256 threads (T overlaid in W's zero lower-left block).
// Phase 3: emit transposed real 128x128 W2t, bf16 hi/lo split.
__global__ __launch_bounds__(256) void cholinv_kernel(const float2* __restrict__ Gc,
                                                      unsigned int* __restrict__ W2h,
                                                      unsigned int* __restrict__ W2l) {
    __shared__ float2 A[64 * 64];    // working Schur -> reused as W (T overlaid lower-left)
    __shared__ float2 Rr[64 * 64];   // finalized R rows
    const int t = threadIdx.x;
    const int w = t >> 6, l = t & 63;

    {   // stage G into A
        const float4* G4 = reinterpret_cast<const float4*>(Gc);
        float4* A4 = reinterpret_cast<float4*>(A);
#pragma unroll
        for (int it = 0; it < 8; ++it) A4[t + 256 * it] = G4[t + 256 * it];
    }
    __syncthreads();

    // ---- Cholesky ----
    for (int i = 0; i < 64; ++i) {
        const float2 rowi = A[i * 64 + l];           // raw row i (barrier-current)
        const float dsq = lane_bcast(rowi.x, i);
        const float d = sqrtf(fmaxf(dsq, 1e-30f));
        const float dinv = 1.0f / d;
        float2 rr;                                   // R[i][l]
        rr.x = rowi.x * dinv;
        rr.y = rowi.y * dinv;
        if (l == i) { rr.x = d; rr.y = 0.f; }
        if (w == 0) {
            float2 st = rr;
            if (l == i) st.y = dinv;                 // pack dinv
            Rr[i * 64 + l] = st;
        }
#pragma unroll 2
        for (int j = i + 1 + w; j < 64; j += 4) {    // wave-split trailing update
            const float rjx = lane_bcast(rr.x, j);
            const float rjy = lane_bcast(rr.y, j);
            float2 v = A[j * 64 + l];
            v.x = fmaf(-rjx, rr.x, fmaf(-rjy, rr.y, v.x));
            v.y = fmaf(-rjx, rr.y, fmaf( rjy, rr.x, v.y));
            A[j * 64 + l] = v;
        }
        __syncthreads();
    }

    // ---- diagonal-block inverses (waves 0,1), column-per-lane ----
    if (w < 2 && l < 32) {
        const int base = 32 * w;
        const int k = base + l;                      // absolute column
        for (int i2 = 31; i2 >= 0; --i2) {
            const int i = base + i2;
            const float2 rowi = Rr[i * 64 + k];      // lane l holds R[i][base+l]
            float2 s = make_float2(0.f, 0.f);
#pragma unroll 2
            for (int j2 = i2 + 1; j2 < 32; ++j2) {
                const float rjx = lane_bcast(rowi.x, j2);
                const float rjy = lane_bcast(rowi.y, j2);
                const float2 wv = A[(base + j2) * 64 + k];
                s.x = fmaf(rjx, wv.x, fmaf(-rjy, wv.y, s.x));
                s.y = fmaf(rjx, wv.y, fmaf( rjy, wv.x, s.y));
            }
            const float di = lane_bcast(rowi.y, i2); // dinv_i
            float2 wi = (l == i2) ? make_float2(di, 0.f)
                                  : make_float2(-di * s.x, -di * s.y);
            A[i * 64 + k] = wi;                      // W[i][k]
        }
    }
    __syncthreads();

    // ---- T = R12 * W22 -> overlay at A[(32+r)*64 + c] (zero lower-left block) ----
    {
        const int c = t & 31;
        const int r0 = (t >> 5) * 4;
        float2 acc[4];
#pragma unroll
        for (int q = 0; q < 4; ++q) acc[q] = make_float2(0.f, 0.f);
        for (int j = 0; j < 32; ++j) {
            const float2 wv = A[(32 + j) * 64 + 32 + c];     // W22[j][c], per-lane
#pragma unroll
            for (int q = 0; q < 4; ++q) {
                const float2 rv = Rr[(r0 + q) * 64 + 32 + j]; // R12[r][j], uniform
                acc[q].x = fmaf(rv.x, wv.x, fmaf(-rv.y, wv.y, acc[q].x));
                acc[q].y = fmaf(rv.x, wv.y, fmaf( rv.y, wv.x, acc[q].y));
            }
        }
#pragma unroll
        for (int q = 0; q < 4; ++q) A[(32 + r0 + q) * 64 + c] = acc[q];
    }
    __syncthreads();

    // ---- W12 = -W11 * T -> A[r*64 + 32 + c] ----
    {
        const int c = t & 31;
        const int r0 = (t >> 5) * 4;
        float2 acc[4];
#pragma unroll
        for (int q = 0; q < 4; ++q) acc[q] = make_float2(0.f, 0.f);
        for (int p = 0; p < 32; ++p) {
            const float2 tv = A[(32 + p) * 64 + c];           // T[p][c], per-lane
#pragma unroll
            for (int q = 0; q < 4; ++q) {
                const float2 uv = A[(r0 + q) * 64 + p];       // W11[r][p], uniform
                acc[q].x = fmaf(uv.x, tv.x, fmaf(-uv.y, tv.y, acc[q].x));
                acc[q].y = fmaf(uv.x, tv.y, fmaf( uv.y, tv.x, acc[q].y));
            }
        }
#pragma unroll
        for (int q = 0; q < 4; ++q)
            A[(r0 + q) * 64 + 32 + c] = make_float2(-acc[q].x, -acc[q].y);
    }
    __syncthreads();

    // ---- emit W2t (transposed real 128x128), bf16 hi/lo split ----
    for (int e = t; e < 4096; e += 256) {
        const int k = e & 63, j = e >> 6;            // W[j][k], j = row
        const float2 v = (j <= k) ? A[j * 64 + k] : make_float2(0.f, 0.f);
        const float wr = v.x, wi = v.y;
        const unsigned short wr_h = f2bf(wr);
        const unsigned short wr_l = f2bf(wr - bf2f(wr_h));
        const unsigned short wi_h = f2bf(wi);
        const unsigned short wi_l = f2bf(wi - bf2f(wi_h));
        const unsigned short nwi_h = f2bf(-wi);
        const unsigned short nwi_l = f2bf(-wi - bf2f(nwi_h));
        const unsigned int row0 = (unsigned int)(2 * k) * 64;
        const unsigned int row1 = row0 + 64;
        W2h[row0 + j] = (unsigned int)wr_h | ((unsigned int)nwi_h << 16);
        W2l[row0 + j] = (unsigned int)wr_l | ((unsigned int)nwi_l << 16);
        W2h[row1 + j] = (unsigned int)wi_h | ((unsigned int)wr_h << 16);
        W2l[row1 + j] = (unsigned int)wi_l | ((unsigned int)wr_l << 16);
    }
}

// ---------------- Q = Y * W2t via MFMA, W-frags hoisted to VGPRs, no LDS ----------------
#define AP_BLOCKS 1024
#define AP_RTILES (M_ROWS / 16 / AP_BLOCKS)  // 16

__global__ __launch_bounds__(256) void apply_mfma(const float* __restrict__ X,
                                                  const unsigned short* __restrict__ W2h,
                                                  const unsigned short* __restrict__ W2l,
                                                  float* __restrict__ Q) {
    const int t = threadIdx.x;
    const int w = t >> 6, l = t & 63, r = l & 15, c = l >> 4;

    bf16x8 bh[2][4], bl[2][4];
#pragma unroll
    for (int ct = 0; ct < 2; ++ct)
#pragma unroll
        for (int kc = 0; kc < 4; ++kc) {
            const int idx = (32 * w + 16 * ct + r) * 128 + kc * 32 + c * 8;
            bh[ct][kc] = *reinterpret_cast<const bf16x8*>(W2h + idx);
            bl[ct][kc] = *reinterpret_cast<const bf16x8*>(W2l + idx);
        }

    const size_t m0 = (size_t)blockIdx.x * (AP_RTILES * 16);
    const float* p = X + (m0 + r) * 128 + c * 8;
    float* qp = Q + (m0 + 4 * c) * 128 + 32 * w + r;

    for (int tt = 0; tt < AP_RTILES; ++tt) {
        bf16x8 ah[4], al[4];
#pragma unroll
        for (int kc = 0; kc < 4; ++kc) {
            const float4 v0 = *reinterpret_cast<const float4*>(p + kc * 32);
            const float4 v1 = *reinterpret_cast<const float4*>(p + kc * 32 + 4);
            const float x[8] = {v0.x, v0.y, v0.z, v0.w, v1.x, v1.y, v1.z, v1.w};
#pragma unroll
            for (int i = 0; i < 8; ++i) {
                const unsigned short h = f2bf(x[i]);
                ah[kc][i] = (short)h;
                al[kc][i] = (short)f2bf(x[i] - bf2f(h));
            }
        }
        f32x4 acc[2];
        acc[0] = (f32x4){0.f, 0.f, 0.f, 0.f};
        acc[1] = (f32x4){0.f, 0.f, 0.f, 0.f};
#pragma unroll
        for (int kc = 0; kc < 4; ++kc)
#pragma unroll
            for (int ct = 0; ct < 2; ++ct) {
                acc[ct] = __builtin_amdgcn_mfma_f32_16x16x32_bf16(ah[kc], bh[ct][kc], acc[ct], 0, 0, 0);
                acc[ct] = __builtin_amdgcn_mfma_f32_16x16x32_bf16(ah[kc], bl[ct][kc], acc[ct], 0, 0, 0);
                acc[ct] = __builtin_amdgcn_mfma_f32_16x16x32_bf16(al[kc], bh[ct][kc], acc[ct], 0, 0, 0);
            }
#pragma unroll
        for (int ct = 0; ct < 2; ++ct)
#pragma unroll
            for (int q = 0; q < 4; ++q)
                qp[q * 128 + ct * 16] = acc[ct][q];
        p += 16 * 128;
        qp += 16 * 128;
    }
}

extern "C" void kernel_launch(void* const* d_in, const int* in_sizes, int n_in,
                              void* d_out, int out_size, void* d_ws, size_t ws_size,
                              hipStream_t stream) {
    (void)in_sizes; (void)n_in; (void)out_size;
    const float* X = reinterpret_cast<const float*>(d_in[0]);
    float* Q = reinterpret_cast<float*>(d_out);

    const size_t extra = 98304;  // Gc 32K + W2h 32K + W2l 32K
    int nbuf = 1;
    while (nbuf < 16 && (size_t)(nbuf * 2) * 65536 + extra <= ws_size) nbuf <<= 1;
    float* Sbufs = reinterpret_cast<float*>(d_ws);
    char* pextra = (char*)d_ws + (size_t)nbuf * 65536;
    float2* Gc = reinterpret_cast<float2*>(pextra);
    unsigned int* W2h = reinterpret_cast<unsigned int*>(pextra + 32768);
    unsigned int* W2l = reinterpret_cast<unsigned int*>(pextra + 65536);

    hipMemsetAsync(Sbufs, 0, (size_t)nbuf * 65536, stream);
    gram_mfma<<<GR_BLOCKS, 256, 0, stream>>>(X, Sbufs, nbuf - 1);
    reduce_g<<<16, 256, 0, stream>>>(Sbufs, nbuf, Gc);
    cholinv_kernel<<<1, 256, 0, stream>>>(Gc, W2h, W2l);
    apply_mfma<<<AP_BLOCKS, 256, 0, stream>>>(X, reinterpret_cast<const unsigned short*>(W2h),
                                              reinterpret_cast<const unsigned short*>(W2l), Q);
}